// Round 5
// baseline (7081.332 us; speedup 1.0000x reference)
//
#include <hip/hip_runtime.h>
#include <float.h>

#define V 50000
#define E 100
#define H 512
#define T 200
#define B 256
#define NC 5
#define K0 640            // layer0 concat-K: 128 (emb pad) + 512
#define K1 1024           // layer1 concat-K: 512 + 512
#define NH (B * H)        // 131072
#define NW0 (2048 * K0)
#define NW1 (2048 * K1)
#define LOSC 4096.0f      // lo-plane scale (2^12) keeps lo out of fp16 denormals
#define ILOSC (1.0f / 4096.0f)
#define NBLK 256          // persistent grid size (1 block / CU)
#define HSLOT (NH * 2)    // halves per h slot (hi+lo interleaved)

typedef _Float16 half8 __attribute__((ext_vector_type(8)));
typedef float floatx4 __attribute__((ext_vector_type(4)));
typedef unsigned long long u64;

// ---------------- activations ----------------
__device__ __forceinline__ float fsig(float x)  { return 1.f / (1.f + __expf(-x)); }
__device__ __forceinline__ float ftanh(float x) { return 1.f - 2.f / (__expf(2.f * x) + 1.f); }

// ---------------- coherence-point access helpers (agent-scope relaxed = sc1) ----
// These bypass the per-XCD L2 and are served at the MALL: cross-XCD coherent
// AND they never evict the L2-resident weight set.
__device__ __forceinline__ half8 ld_h8_cc(const _Float16* p) {
    u64 a = __hip_atomic_load((const u64*)p,       __ATOMIC_RELAXED, __HIP_MEMORY_SCOPE_AGENT);
    u64 b = __hip_atomic_load(((const u64*)p) + 1, __ATOMIC_RELAXED, __HIP_MEMORY_SCOPE_AGENT);
    union { u64 u[2]; half8 h; } x; x.u[0] = a; x.u[1] = b; return x.h;
}
__device__ __forceinline__ float4 ld_f4_cc(const float* p) {
    u64 a = __hip_atomic_load((const u64*)p,       __ATOMIC_RELAXED, __HIP_MEMORY_SCOPE_AGENT);
    u64 b = __hip_atomic_load(((const u64*)p) + 1, __ATOMIC_RELAXED, __HIP_MEMORY_SCOPE_AGENT);
    union { u64 u[2]; float4 f; } x; x.u[0] = a; x.u[1] = b; return x.f;
}
__device__ __forceinline__ void st_u64_cc(void* p, u64 v) {
    __hip_atomic_store((u64*)p, v, __ATOMIC_RELAXED, __HIP_MEMORY_SCOPE_AGENT);
}

// ---------------- workspace map ----------------
// h layout (hi/lo interleaved): h[slot][b][H/8] records of 16 halves:
//   halves 0..7 = hi of j-chunk, 8..15 = lo.  (round-3 proven layout)
struct WS {
    _Float16 *W0h, *W0l, *W1h, *W1l;   // [2048][K] split planes, c = j*4+g
    _Float16 *h0, *h1;                 // [2 slots][B][H/8][16] interleaved
    float *hmax;                       // [B][H]
    int *last;                         // [B]
    unsigned *arr;                     // [NBLK] arrival words (sc1)
    unsigned *gen;                     // generation word (sc1, own line)
    unsigned *claim;                   // [8] per-XCD slot-claim counters (sc1)
};
__device__ __host__ inline WS wsmap(char* p) {
    WS w;
    w.W0h = (_Float16*)p;  p += (size_t)NW0 * 2;
    w.W0l = (_Float16*)p;  p += (size_t)NW0 * 2;
    w.W1h = (_Float16*)p;  p += (size_t)NW1 * 2;
    w.W1l = (_Float16*)p;  p += (size_t)NW1 * 2;
    w.h0  = (_Float16*)p;  p += (size_t)2 * HSLOT * 2;   // 1 MiB
    w.h1  = (_Float16*)p;  p += (size_t)2 * HSLOT * 2;   // 1 MiB
    w.hmax = (float*)p;    p += (size_t)NH * 4;
    w.last = (int*)p;      p += (size_t)B * 4;
    w.arr   = (unsigned*)p;               // +0    .. +1023
    w.gen   = (unsigned*)(p + 1024);      // +1024 (own 128B line)
    w.claim = (unsigned*)(p + 1152);      // +1152 .. +1183
    return w;
}

// ---------------- prep: split weights into fp16 hi/lo catenated layout ----------------
__global__ void k_prep(const float* __restrict__ Wih0, const float* __restrict__ Whh0,
                       const float* __restrict__ Wih1, const float* __restrict__ Whh1,
                       char* wsraw) {
    WS w = wsmap(wsraw);
    int idx = blockIdx.x * 256 + threadIdx.x;
    if (idx < NW0) {
        int c = idx / K0, k = idx - c * K0;
        int jx = c >> 2, g = c & 3, row = g * H + jx;
        float v = 0.f;
        if (k < 128) { if (k < E) v = Wih0[(size_t)row * E + k]; }
        else           v = Whh0[(size_t)row * H + (k - 128)];
        _Float16 hh = (_Float16)v;
        w.W0h[idx] = hh;
        w.W0l[idx] = (_Float16)((v - (float)hh) * LOSC);
    } else if (idx < NW0 + NW1) {
        int i2 = idx - NW0;
        int c = i2 / K1, k = i2 - c * K1;
        int jx = c >> 2, g = c & 3, row = g * H + jx;
        float v = (k < H) ? Wih1[(size_t)row * H + k]
                          : Whh1[(size_t)row * H + (k - H)];
        _Float16 hh = (_Float16)v;
        w.W1h[i2] = hh;
        w.W1l[i2] = (_Float16)((v - (float)hh) * LOSC);
    }
}

// ---------------- init: zero h planes, last[b], barrier/claim words ----------------
__global__ void k_init(const int* __restrict__ X, char* wsraw) {
    WS w = wsmap(wsraw);
    int i = blockIdx.x * 256 + threadIdx.x;
    if (i < 524288) ((unsigned*)w.h0)[i] = 0u;   // h0,h1 contiguous = 2 MiB
    if (i < 512)    w.arr[i] = 0u;               // arr + gen + claim (2KB)
    if (i < B) {
        int l = -1;
        const int* xr = X + i * T;
        for (int t = 0; t < T; ++t) if (xr[t] != V) l = t;
        w.last[i] = l;
    }
}

// ---------------- count-agnostic grid barrier (round-3 proven) ----------------
__device__ __forceinline__ void pre_barrier(unsigned* arr, unsigned* gen,
                                            int bid, int tid, unsigned tgt) {
    asm volatile("s_waitcnt vmcnt(0)" ::: "memory");
    __syncthreads();
    if (tid == 0)
        __hip_atomic_store(&arr[bid], tgt, __ATOMIC_RELAXED, __HIP_MEMORY_SCOPE_AGENT);
    if (bid == 0) {
        if (tid < 64) {
            for (;;) {
                unsigned f0 = __hip_atomic_load(&arr[tid],       __ATOMIC_RELAXED, __HIP_MEMORY_SCOPE_AGENT);
                unsigned f1 = __hip_atomic_load(&arr[tid + 64],  __ATOMIC_RELAXED, __HIP_MEMORY_SCOPE_AGENT);
                unsigned f2 = __hip_atomic_load(&arr[tid + 128], __ATOMIC_RELAXED, __HIP_MEMORY_SCOPE_AGENT);
                unsigned f3 = __hip_atomic_load(&arr[tid + 192], __ATOMIC_RELAXED, __HIP_MEMORY_SCOPE_AGENT);
                bool ok = (f0 >= tgt) & (f1 >= tgt) & (f2 >= tgt) & (f3 >= tgt);
                if (__all(ok)) break;
                __builtin_amdgcn_s_sleep(2);
            }
            if (tid == 0)
                __hip_atomic_store(gen, tgt, __ATOMIC_RELAXED, __HIP_MEMORY_SCOPE_AGENT);
        }
    } else {
        if (tid == 0) {
            while (__hip_atomic_load(gen, __ATOMIC_RELAXED, __HIP_MEMORY_SCOPE_AGENT) < tgt)
                __builtin_amdgcn_s_sleep(4);
        }
    }
    __syncthreads();
    asm volatile("" ::: "memory");
}

// ---------------- prefetch of next step's h-independent fragments ----------------
// A (weights) via L2-cached loads; layer-0 emb via sc1 (MALL) so the random
// gather never evicts the weight working set from L2.
template <int LAYER>
struct Pref { half8 Ah[4], Al[4], Bh[4], Bl[4]; };

template <int LAYER>
__device__ __forceinline__ void prefetch0(
    int t, const int* __restrict__ X, const float* __restrict__ emb,
    const _Float16* __restrict__ Wh, const _Float16* __restrict__ Wl,
    int c0g, int b0gl, int m, int qq, int wq, Pref<LAYER>& P)
{
    const int KT = LAYER ? K1 : K0;
    const int ko = wq * 32 + qq * 8;              // kb = wq
#pragma unroll
    for (int cs = 0; cs < 4; ++cs) {
        const size_t ro = (size_t)(c0g + cs * 16 + m) * KT + ko;
        P.Ah[cs] = *(const half8*)(Wh + ro);
        P.Al[cs] = *(const half8*)(Wl + ro);
    }
    if (LAYER == 0) {                             // kb = wq < 4 -> emb, convert now
#pragma unroll
        for (int bs = 0; bs < 4; ++bs) {
            int er = X[(b0gl + bs * 16 + m) * T + t];
            const float* p = emb + (size_t)er * E;
            float4 fa = make_float4(0.f,0.f,0.f,0.f), fb = fa;
            if (ko <= 96) fa = ld_f4_cc(p + ko);
            if (ko <= 92) fb = ld_f4_cc(p + ko + 4);
            float e[8] = {fa.x,fa.y,fa.z,fa.w, fb.x,fb.y,fb.z,fb.w};
#pragma unroll
            for (int u = 0; u < 8; ++u) {
                _Float16 hv = (_Float16)e[u];
                P.Bh[bs][u] = hv;
                P.Bl[bs][u] = (_Float16)((e[u] - (float)hv) * LOSC);
            }
        }
    }
}

// ---------------- K-quarter MFMA loop (per wave) ----------------
template <int LAYER>
__device__ __forceinline__ void run_mm(
    const Pref<LAYER>& P,
    const _Float16* __restrict__ Wh, const _Float16* __restrict__ Wl,
    const _Float16* __restrict__ x0, const _Float16* __restrict__ x1,
    int c0g, int b0gl, int m, int qq, int wq,
    floatx4 (&acc0)[16], floatx4 (&acc1)[16])
{
    const int KT  = LAYER ? K1 : K0;
    const int NKB = LAYER ? 8 : 5;    // k-blocks of 32 per wave (kb = wq + 4*i)
    half8 A_h[2][4], A_l[2][4], B_h[2][4], B_l[2][4];

    auto ldA = [&](int kb, int buf) {
        const int ko = kb * 32 + qq * 8;
#pragma unroll
        for (int cs = 0; cs < 4; ++cs) {
            const size_t ro = (size_t)(c0g + cs * 16 + m) * KT + ko;
            A_h[buf][cs] = *(const half8*)(Wh + ro);
            A_l[buf][cs] = *(const half8*)(Wl + ro);
        }
    };
    auto ldB = [&](int kb, int buf) {             // h-records only
        const int ko = kb * 32 + qq * 8;
        const _Float16* sx; int kk;
        if (LAYER == 0)   { sx = x0; kk = ko - 128; }
        else if (kb < 16) { sx = x0; kk = ko; }
        else              { sx = x1; kk = ko - 512; }
        const int ch = kk >> 3;
#pragma unroll
        for (int bs = 0; bs < 4; ++bs) {
            const _Float16* bp = sx + ((size_t)(b0gl + bs * 16 + m) * (H/8) + ch) * 16;
            B_h[buf][bs] = ld_h8_cc(bp);
            B_l[buf][bs] = ld_h8_cc(bp + 8);
        }
    };

    // buf0: A (and layer0 emb-B) from prefetch; layer1 B loaded now (needs fresh h)
#pragma unroll
    for (int cs = 0; cs < 4; ++cs) { A_h[0][cs] = P.Ah[cs]; A_l[0][cs] = P.Al[cs]; }
    if (LAYER == 0) {
#pragma unroll
        for (int bs = 0; bs < 4; ++bs) { B_h[0][bs] = P.Bh[bs]; B_l[0][bs] = P.Bl[bs]; }
    } else {
        ldB(wq, 0);
    }

#pragma unroll
    for (int i = 0; i < NKB; ++i) {
        const int cur = i & 1;
        if (i + 1 < NKB) { ldA(wq + 4 * (i + 1), cur ^ 1); ldB(wq + 4 * (i + 1), cur ^ 1); }
#pragma unroll
        for (int cs = 0; cs < 4; ++cs)
#pragma unroll
            for (int bs = 0; bs < 4; ++bs) {
                const int ti = cs * 4 + bs;
                acc0[ti] = __builtin_amdgcn_mfma_f32_16x16x32_f16(A_h[cur][cs], B_h[cur][bs], acc0[ti], 0, 0, 0);
                acc1[ti] = __builtin_amdgcn_mfma_f32_16x16x32_f16(A_h[cur][cs], B_l[cur][bs], acc1[ti], 0, 0, 0);
                acc1[ti] = __builtin_amdgcn_mfma_f32_16x16x32_f16(A_l[cur][cs], B_h[cur][bs], acc1[ti], 0, 0, 0);
            }
    }
}

// ---------------- persistent fused kernel ----------------
// Slot assignment: each block claims a slot n in its PHYSICAL XCD's pool
// (s_getreg XCC_ID). After a count-agnostic pre-barrier, all blocks validate
// claim[x]==32 for all x; if balanced -> XCD-local mapping (weights 3.4MB/XCD,
// L2-resident); else -> uniform fallback to the bid-based round-3 mapping.
// Neither path can deadlock or double-compute.
__global__ __launch_bounds__(256, 1) void k_lstm(
    const int* __restrict__ X, const float* __restrict__ emb,
    const float* __restrict__ b0, const float* __restrict__ b1,
    char* __restrict__ wsraw)
{
    extern __shared__ float red[];    // [4 waves][64 b][68]  (c-minor, +4 pad)
    __shared__ int s_info, s_ok;

    const int tid = threadIdx.x, lane = tid & 63, wq = tid >> 6;
    const int m = lane & 15, qq = lane >> 4;
    const int bid = blockIdx.x;

    WS w = wsmap(wsraw);

    // ---- claim a slot in this block's physical XCD pool ----
    if (tid == 0) {
        unsigned xcc;
        asm volatile("s_getreg_b32 %0, hwreg(HW_REG_XCC_ID)" : "=s"(xcc));
        xcc &= 7u;
        unsigned n = __hip_atomic_fetch_add(&w.claim[xcc], 1u,
                        __ATOMIC_RELAXED, __HIP_MEMORY_SCOPE_AGENT);
        s_info = (int)((xcc << 8) | (n & 255u));
    }
    pre_barrier(w.arr, w.gen, bid, tid, 1u);     // all claims now final & visible
    if (tid == 0) {
        int okc = 1;
#pragma unroll
        for (int x = 0; x < 8; ++x)
            okc &= (__hip_atomic_load(&w.claim[x], __ATOMIC_RELAXED,
                                      __HIP_MEMORY_SCOPE_AGENT) == 32u) ? 1 : 0;
        s_ok = okc;
    }
    __syncthreads();

    int xcd, slot;
    if (s_ok) { xcd = (s_info >> 8) & 7; slot = s_info & 31; }
    else      { xcd = bid & 7;           slot = bid >> 3;    }
    const int layer = slot >> 4, bblk = (slot >> 2) & 3, chi = slot & 3;
    const int cblk = chi * 8 + xcd;
    const int c0g = cblk * 64, b0gl = bblk * 64, j0g = cblk * 16;

    // ---- epilogue lane mapping: lane owns (1 b) x (4 contiguous j) ----
    const int b16 = lane & 15, jq = lane >> 4;
    const int bl_e = wq * 16 + b16;
    const int bg_e = b0gl + bl_e;
    const int jb = jq * 4;
    const int ch_e  = (j0g + jb) >> 3;            // h record chunk
    const int hsel  = (jb >> 2) & 1;              // quad within chunk
    const float* bias = layer ? b1 : b0;
    float bv[4][4];
#pragma unroll
    for (int g = 0; g < 4; ++g)
#pragma unroll
        for (int u = 0; u < 4; ++u)
            bv[g][u] = bias[g * H + j0g + jb + u];

    float creg[4], hmreg[4];
#pragma unroll
    for (int u = 0; u < 4; ++u) { creg[u] = 0.f; hmreg[u] = -FLT_MAX; }
    const int lastb = w.last[bg_e];

    Pref<0> P0; Pref<1> P1;
    if (layer == 0) prefetch0<0>(0, X, emb, w.W0h, w.W0l, c0g, b0gl, m, qq, wq, P0);

    for (int t = 0; t <= T; ++t) {
        const int tt = t - 1;
        const bool act = layer ? (t >= 1) : (t < T);
        if (act) {
            floatx4 acc0[16], acc1[16];
#pragma unroll
            for (int i = 0; i < 16; ++i) {
                floatx4 z = {0.f, 0.f, 0.f, 0.f};
                acc0[i] = z; acc1[i] = z;
            }

            if (layer == 0)
                run_mm<0>(P0, w.W0h, w.W0l,
                          w.h0 + (size_t)((t + 1) & 1) * HSLOT, nullptr,
                          c0g, b0gl, m, qq, wq, acc0, acc1);
            else
                run_mm<1>(P1, w.W1h, w.W1l,
                          w.h0 + (size_t)(tt & 1) * HSLOT,
                          w.h1 + (size_t)((tt + 1) & 1) * HSLOT,
                          c0g, b0gl, m, qq, wq, acc0, acc1);

            // ---- fold lo-acc, dump k-quarter partials ----
#pragma unroll
            for (int cs = 0; cs < 4; ++cs)
#pragma unroll
                for (int bs = 0; bs < 4; ++bs) {
                    floatx4 v = acc0[cs * 4 + bs] + acc1[cs * 4 + bs] * ILOSC;
                    const int bl = bs * 16 + m, cl = cs * 16 + qq * 4;
                    *(floatx4*)&red[((wq * 64 + bl) * 68 + cl)] = v;
                }
            __syncthreads();

            // ---- reduce 4 quarters + epilogue ----
            _Float16* o = (layer ? w.h1 + (size_t)(tt & 1) * HSLOT
                                 : w.h0 + (size_t)(t  & 1) * HSLOT);
            float hn4[4];
#pragma unroll
            for (int u = 0; u < 4; ++u) {
                floatx4 g = *(floatx4*)&red[((0 * 64 + bl_e) * 68 + (jb + u) * 4)];
#pragma unroll
                for (int q2 = 1; q2 < 4; ++q2)
                    g += *(floatx4*)&red[((q2 * 64 + bl_e) * 68 + (jb + u) * 4)];
                float ig = fsig (g.x + bv[0][u]);
                float fg = fsig (g.y + bv[1][u]);
                float gg = ftanh(g.z + bv[2][u]);
                float og = fsig (g.w + bv[3][u]);
                float cn = fg * creg[u] + ig * gg;
                float hn = og * ftanh(cn);
                creg[u] = cn;
                hn4[u] = hn;
            }
            if (layer == 1 && tt <= lastb) {
#pragma unroll
                for (int u = 0; u < 4; ++u) hmreg[u] = fmaxf(hmreg[u], hn4[u]);
            }
            union { _Float16 h[4]; u64 uu; } ph, pl;
#pragma unroll
            for (int u = 0; u < 4; ++u) {
                _Float16 hh = (_Float16)hn4[u];
                ph.h[u] = hh;
                pl.h[u] = (_Float16)((hn4[u] - (float)hh) * LOSC);
            }
            _Float16* rec = o + ((size_t)bg_e * (H/8) + ch_e) * 16 + hsel * 4;
            st_u64_cc(rec,     ph.uu);            // hi quad
            st_u64_cc(rec + 8, pl.uu);            // lo quad (same 32B record)
        }

        if (t < T) {
            // ---- barrier arrive: drain sc1 h-stores, publish arrival ----
            asm volatile("s_waitcnt vmcnt(0)" ::: "memory");
            __syncthreads();
            const unsigned tgt = (unsigned)(t + 2);   // pre-barrier used tgt=1
            if (tid == 0)
                __hip_atomic_store(&w.arr[bid], tgt, __ATOMIC_RELAXED, __HIP_MEMORY_SCOPE_AGENT);

            // ---- barrier-overlapped prefetch for iteration t+1 ----
            const int nt = t + 1;
            if (layer == 0) { if (nt < T) prefetch0<0>(nt, X, emb, w.W0h, w.W0l, c0g, b0gl, m, qq, wq, P0); }
            else            prefetch0<1>(0, X, emb, w.W1h, w.W1l, c0g, b0gl, m, qq, wq, P1);

            // ---- barrier wait: block 0 aggregates, others poll one word ----
            if (bid == 0) {
                if (tid < 64) {
                    for (;;) {
                        unsigned f0 = __hip_atomic_load(&w.arr[tid],       __ATOMIC_RELAXED, __HIP_MEMORY_SCOPE_AGENT);
                        unsigned f1 = __hip_atomic_load(&w.arr[tid + 64],  __ATOMIC_RELAXED, __HIP_MEMORY_SCOPE_AGENT);
                        unsigned f2 = __hip_atomic_load(&w.arr[tid + 128], __ATOMIC_RELAXED, __HIP_MEMORY_SCOPE_AGENT);
                        unsigned f3 = __hip_atomic_load(&w.arr[tid + 192], __ATOMIC_RELAXED, __HIP_MEMORY_SCOPE_AGENT);
                        bool ok = (f0 >= tgt) & (f1 >= tgt) & (f2 >= tgt) & (f3 >= tgt);
                        if (__all(ok)) break;
                        __builtin_amdgcn_s_sleep(2);
                    }
                    if (tid == 0)
                        __hip_atomic_store(w.gen, tgt, __ATOMIC_RELAXED, __HIP_MEMORY_SCOPE_AGENT);
                }
            } else {
                if (tid == 0) {
                    while (__hip_atomic_load(w.gen, __ATOMIC_RELAXED, __HIP_MEMORY_SCOPE_AGENT) < tgt)
                        __builtin_amdgcn_s_sleep(4);
                }
            }
            __syncthreads();
            asm volatile("" ::: "memory");
        }
    }

    // ---- write out register-resident maxpool state ----
    if (layer == 1) {
        float4 hv = make_float4(hmreg[0], hmreg[1], hmreg[2], hmreg[3]);
        *(float4*)(w.hmax + (size_t)bg_e * H + j0g + jb) = hv;
    }
}

// ---------------- final: logits ----------------
__global__ __launch_bounds__(64) void k_out(const float* __restrict__ hmax,
                                            const float* __restrict__ Wout,
                                            const float* __restrict__ bout,
                                            float* __restrict__ out) {
    const int b = blockIdx.x * 64 + threadIdx.x;
    float a[NC] = {0.f, 0.f, 0.f, 0.f, 0.f};
    const float* hm = hmax + (size_t)b * H;
    for (int j = 0; j < H; ++j) {
        float hv = hm[j];
#pragma unroll
        for (int cls = 0; cls < NC; ++cls)
            a[cls] = fmaf(hv, Wout[cls * H + j], a[cls]);
    }
#pragma unroll
    for (int cls = 0; cls < NC; ++cls)
        out[b * NC + cls] = a[cls] + bout[cls];
}

// ---------------- launch ----------------
extern "C" void kernel_launch(void* const* d_in, const int* in_sizes, int n_in,
                              void* d_out, int out_size, void* d_ws, size_t ws_size,
                              hipStream_t stream) {
    const int*   X    = (const int*)  d_in[0];
    const float* emb  = (const float*)d_in[1];
    const float* Wih0 = (const float*)d_in[2];
    const float* Whh0 = (const float*)d_in[3];
    const float* b0   = (const float*)d_in[4];
    const float* Wih1 = (const float*)d_in[5];
    const float* Whh1 = (const float*)d_in[6];
    const float* b1   = (const float*)d_in[7];
    const float* Wout = (const float*)d_in[8];
    const float* bout = (const float*)d_in[9];
    float* out = (float*)d_out;
    char* ws = (char*)d_ws;
    WS w = wsmap(ws);

    k_prep<<<(NW0 + NW1 + 255) / 256, 256, 0, stream>>>(Wih0, Whh0, Wih1, Whh1, ws);
    k_init<<<2048, 256, 0, stream>>>(X, ws);

    {
        const unsigned smem = (unsigned)(4 * 64 * 68 * sizeof(float));  // 69,632 B (round-3 proven)
        void* args[] = {(void*)&X, (void*)&emb, (void*)&b0, (void*)&b1, (void*)&ws};
        hipError_t e = hipLaunchCooperativeKernel((const void*)k_lstm, dim3(NBLK), dim3(256),
                                                  args, smem, stream);
        if (e != hipSuccess) {
            k_lstm<<<NBLK, 256, smem, stream>>>(X, emb, b0, b1, ws);
        }
    }

    k_out<<<4, 64, 0, stream>>>(w.hmax, Wout, bout, out);
}

// Round 6
// 4870.059 us; speedup vs baseline: 1.4541x; 1.4541x over previous
//
#include <hip/hip_runtime.h>
#include <float.h>

#define V 50000
#define E 100
#define H 512
#define T 200
#define B 256
#define NC 5
#define K0 640            // layer0 concat-K: 128 (emb pad) + 512
#define K1 1024           // layer1 concat-K: 512 + 512
#define NH (B * H)        // 131072
#define NW0 (2048 * K0)
#define NW1 (2048 * K1)
#define LOSC 4096.0f      // lo-plane scale (2^12) keeps lo out of fp16 denormals
#define ILOSC (1.0f / 4096.0f)

typedef _Float16 half8 __attribute__((ext_vector_type(8)));
typedef float floatx4 __attribute__((ext_vector_type(4)));

// ---------------- activations ----------------
__device__ __forceinline__ float fsig(float x)  { return 1.f / (1.f + __expf(-x)); }
__device__ __forceinline__ float ftanh(float x) { return 1.f - 2.f / (__expf(2.f * x) + 1.f); }

// ---------------- workspace map (round-0 proven) ----------------
struct WS {
    _Float16 *W0h, *W0l, *W1h, *W1l;   // [2048][K] split planes, c = j*4+g
    _Float16 *h0h, *h0l, *h1h, *h1l;   // [2 slots][B][H] split planes (lo pre-scaled)
    float *c0, *c1, *hmax;             // [B][H]
    int *last;
};
__device__ __host__ inline WS wsmap(char* p) {
    WS w;
    w.W0h = (_Float16*)p;  p += (size_t)NW0 * 2;
    w.W0l = (_Float16*)p;  p += (size_t)NW0 * 2;
    w.W1h = (_Float16*)p;  p += (size_t)NW1 * 2;
    w.W1l = (_Float16*)p;  p += (size_t)NW1 * 2;
    w.h0h = (_Float16*)p;  p += (size_t)2 * NH * 2;
    w.h0l = (_Float16*)p;  p += (size_t)2 * NH * 2;
    w.h1h = (_Float16*)p;  p += (size_t)2 * NH * 2;
    w.h1l = (_Float16*)p;  p += (size_t)2 * NH * 2;
    w.c0   = (float*)p;    p += (size_t)NH * 4;
    w.c1   = (float*)p;    p += (size_t)NH * 4;
    w.hmax = (float*)p;    p += (size_t)NH * 4;
    w.last = (int*)p;
    return w;
}

// ---------------- prep: split weights into fp16 hi/lo catenated layout ----------------
__global__ void k_prep(const float* __restrict__ Wih0, const float* __restrict__ Whh0,
                       const float* __restrict__ Wih1, const float* __restrict__ Whh1,
                       char* wsraw) {
    WS w = wsmap(wsraw);
    int idx = blockIdx.x * 256 + threadIdx.x;
    if (idx < NW0) {
        int c = idx / K0, k = idx - c * K0;
        int jx = c >> 2, g = c & 3, row = g * H + jx;
        float v = 0.f;
        if (k < 128) { if (k < E) v = Wih0[(size_t)row * E + k]; }
        else           v = Whh0[(size_t)row * H + (k - 128)];
        _Float16 hh = (_Float16)v;
        w.W0h[idx] = hh;
        w.W0l[idx] = (_Float16)((v - (float)hh) * LOSC);
    } else if (idx < NW0 + NW1) {
        int i2 = idx - NW0;
        int c = i2 / K1, k = i2 - c * K1;
        int jx = c >> 2, g = c & 3, row = g * H + jx;
        float v = (k < H) ? Wih1[(size_t)row * H + k]
                          : Whh1[(size_t)row * H + (k - H)];
        _Float16 hh = (_Float16)v;
        w.W1h[i2] = hh;
        w.W1l[i2] = (_Float16)((v - (float)hh) * LOSC);
    }
}

// ---------------- init: zero states, hmax=-FLT_MAX, last[b] ----------------
__global__ void k_init(const int* __restrict__ X, char* wsraw) {
    WS w = wsmap(wsraw);
    int i = blockIdx.x * 256 + threadIdx.x;
    if (i < 524288)                     ((unsigned*)w.h0h)[i] = 0u;        // all h planes
    else if (i < 524288 + 262144)       ((unsigned*)w.c0)[i - 524288] = 0u; // c0,c1
    else if (i < 524288 + 262144 + NH)  w.hmax[i - 786432] = -FLT_MAX;
    if (i < B) {
        int l = -1;
        const int* xr = X + i * T;
        for (int t = 0; t < T; ++t) if (xr[t] != V) l = t;
        w.last[i] = l;
    }
}

// ---------------- K-quarter MFMA loop (per wave), cs=2 (32 c-rows/block) ----------
template <int LAYER>
__device__ __forceinline__ void run_mm(
    int t, const int* __restrict__ X, const float* __restrict__ emb,
    const _Float16* __restrict__ Wh, const _Float16* __restrict__ Wl,
    const _Float16* __restrict__ xh0, const _Float16* __restrict__ xl0,
    const _Float16* __restrict__ xh1, const _Float16* __restrict__ xl1,
    int c0g, int b0gl, int m, int qq, int wq,
    floatx4 (&acc0)[8], floatx4 (&acc1)[8])
{
    const int KT  = LAYER ? K1 : K0;
    const int NKB = LAYER ? 8 : 5;    // k-blocks of 32 per wave (kb = wq + 4*i)
    int erow[4];
    if (LAYER == 0) {
#pragma unroll
        for (int bs = 0; bs < 4; ++bs)
            erow[bs] = X[(b0gl + bs * 16 + m) * T + t];
    }
    half8 A_h[2][2], A_l[2][2], B_h[2][4], B_l[2][4];

    auto ldkb = [&](int kb, int buf) {
        const int ko = kb * 32 + qq * 8;
#pragma unroll
        for (int cs = 0; cs < 2; ++cs) {
            const size_t ro = (size_t)(c0g + cs * 16 + m) * KT + ko;
            A_h[buf][cs] = *(const half8*)(Wh + ro);
            A_l[buf][cs] = *(const half8*)(Wl + ro);
        }
        if (LAYER == 0 && kb < 4) {            // embedding part, convert on the fly
#pragma unroll
            for (int bs = 0; bs < 4; ++bs) {
                const float* er = emb + (size_t)erow[bs] * E;
                float4 fa = make_float4(0.f,0.f,0.f,0.f), fb = fa;
                if (ko <= 96) fa = *(const float4*)(er + ko);
                if (ko <= 92) fb = *(const float4*)(er + ko + 4);
                float e[8] = {fa.x,fa.y,fa.z,fa.w, fb.x,fb.y,fb.z,fb.w};
                half8 hh, hl;
#pragma unroll
                for (int u = 0; u < 8; ++u) {
                    _Float16 hv = (_Float16)e[u];
                    hh[u] = hv;
                    hl[u] = (_Float16)((e[u] - (float)hv) * LOSC);
                }
                B_h[buf][bs] = hh; B_l[buf][bs] = hl;
            }
        } else {
            const _Float16 *sh, *sl; int kk;
            if (LAYER == 0)      { sh = xh0; sl = xl0; kk = ko - 128; }
            else if (kb < 16)    { sh = xh0; sl = xl0; kk = ko; }
            else                 { sh = xh1; sl = xl1; kk = ko - 512; }
#pragma unroll
            for (int bs = 0; bs < 4; ++bs) {
                const size_t ro = (size_t)(b0gl + bs * 16 + m) * H + kk;
                B_h[buf][bs] = *(const half8*)(sh + ro);
                B_l[buf][bs] = *(const half8*)(sl + ro);
            }
        }
    };

    ldkb(wq, 0);
#pragma unroll
    for (int i = 0; i < NKB; ++i) {
        const int cur = i & 1;
        if (i + 1 < NKB) ldkb(wq + 4 * (i + 1), cur ^ 1);   // prefetch next k-block
#pragma unroll
        for (int cs = 0; cs < 2; ++cs)
#pragma unroll
            for (int bs = 0; bs < 4; ++bs) {
                const int ti = cs * 4 + bs;
                acc0[ti] = __builtin_amdgcn_mfma_f32_16x16x32_f16(A_h[cur][cs], B_h[cur][bs], acc0[ti], 0, 0, 0);
                acc1[ti] = __builtin_amdgcn_mfma_f32_16x16x32_f16(A_h[cur][cs], B_l[cur][bs], acc1[ti], 0, 0, 0);
                acc1[ti] = __builtin_amdgcn_mfma_f32_16x16x32_f16(A_l[cur][cs], B_h[cur][bs], acc1[ti], 0, 0, 0);
            }
    }
}

// ---------------- fused step: 512 blocks (2/CU), block = (layer, bblk, cblk) ------
// bid = ((layer*4 + bblk)*8 + chi)*8 + xcd, cblk = chi*8+xcd in 0..63 (32 c-rows).
// Halved c-tile -> acc 64 VGPR, LDS 36.9 KB -> 2 blocks/CU co-resident (8 waves/CU)
// to double memory-level parallelism against the per-step weight refetch.
__global__ __launch_bounds__(256, 2) void k_step(
    int t, const int* __restrict__ X, const float* __restrict__ emb,
    const float* __restrict__ b0, const float* __restrict__ b1,
    char* __restrict__ wsraw)
{
    extern __shared__ float red[];    // [4 waves][64 b][36]  (c-minor, +4 pad)

    const int tid = threadIdx.x, lane = tid & 63, wq = tid >> 6;
    const int m = lane & 15, qq = lane >> 4;
    const int bid = blockIdx.x;
    const int xcd = bid & 7, chi = (bid >> 3) & 7;
    const int bblk = (bid >> 6) & 3, layer = bid >> 8;
    const int cblk = chi * 8 + xcd;
    if (layer == 0 && t >= T) return;
    if (layer == 1 && t < 1)  return;
    const int tt = t - 1;
    const int c0g = cblk * 32, b0gl = bblk * 64, j0g = cblk * 8;

    WS w = wsmap(wsraw);

    floatx4 acc0[8], acc1[8];
#pragma unroll
    for (int i = 0; i < 8; ++i) {
        floatx4 z = {0.f, 0.f, 0.f, 0.f};
        acc0[i] = z; acc1[i] = z;
    }

    if (layer == 0)
        run_mm<0>(t, X, emb, w.W0h, w.W0l,
                  w.h0h + (size_t)((t + 1) & 1) * NH, w.h0l + (size_t)((t + 1) & 1) * NH,
                  nullptr, nullptr, c0g, b0gl, m, qq, wq, acc0, acc1);
    else
        run_mm<1>(tt, X, emb, w.W1h, w.W1l,
                  w.h0h + (size_t)(tt & 1) * NH, w.h0l + (size_t)(tt & 1) * NH,
                  w.h1h + (size_t)((tt + 1) & 1) * NH, w.h1l + (size_t)((tt + 1) & 1) * NH,
                  c0g, b0gl, m, qq, wq, acc0, acc1);

    // ---- fold lo-acc, dump k-quarter partials ----
#pragma unroll
    for (int cs = 0; cs < 2; ++cs)
#pragma unroll
        for (int bs = 0; bs < 4; ++bs) {
            floatx4 v = acc0[cs * 4 + bs] + acc1[cs * 4 + bs] * ILOSC;
            const int bl = bs * 16 + m, cl = cs * 16 + qq * 4;
            *(floatx4*)&red[((wq * 64 + bl) * 36 + cl)] = v;
        }
    __syncthreads();

    // ---- reduce 4 quarters + epilogue; wave wq owns b-strip [wq*16, wq*16+16) ----
    // lane = bq*8 + jj: 8 b-slots (bq) x 8 j (jj); bi doubles b coverage to 16.
    const int jj = lane & 7, bq = lane >> 3;
    const int j = j0g + jj;
    const float* bias = layer ? b1 : b0;
    const float bv0 = bias[0 * H + j], bv1 = bias[1 * H + j];
    const float bv2 = bias[2 * H + j], bv3 = bias[3 * H + j];
    float* cst = layer ? w.c1 : w.c0;
    _Float16* oh = layer ? (w.h1h + (size_t)(tt & 1) * NH) : (w.h0h + (size_t)(t & 1) * NH);
    _Float16* ol = layer ? (w.h1l + (size_t)(tt & 1) * NH) : (w.h0l + (size_t)(t & 1) * NH);

#pragma unroll
    for (int bi = 0; bi < 2; ++bi) {
        const int bl = wq * 16 + bq + 8 * bi;     // 8 lanes (jj) share this b
        const int bg = b0gl + bl;
        floatx4 g = *(floatx4*)&red[((0 * 64 + bl) * 36 + jj * 4)];
#pragma unroll
        for (int q2 = 1; q2 < 4; ++q2)
            g += *(floatx4*)&red[((q2 * 64 + bl) * 36 + jj * 4)];
        float ig = fsig (g.x + bv0);
        float fg = fsig (g.y + bv1);
        float gg = ftanh(g.z + bv2);
        float og = fsig (g.w + bv3);
        float cold = cst[(size_t)bg * H + j];
        float cn = fg * cold + ig * gg;
        float hn = og * ftanh(cn);
        cst[(size_t)bg * H + j] = cn;
        _Float16 hh = (_Float16)hn;
        oh[(size_t)bg * H + j] = hh;
        ol[(size_t)bg * H + j] = (_Float16)((hn - (float)hh) * LOSC);
        if (layer == 1 && tt <= w.last[bg]) {
            float* hp = w.hmax + (size_t)bg * H + j;
            *hp = fmaxf(*hp, hn);
        }
    }
}

// ---------------- final: logits[b][cls] = sum_j hmax[b][j] * Wout[cls][j] + bout ----
__global__ __launch_bounds__(64) void k_out(const float* __restrict__ hmax,
                                            const float* __restrict__ Wout,
                                            const float* __restrict__ bout,
                                            float* __restrict__ out) {
    const int b = blockIdx.x * 64 + threadIdx.x;
    float a[NC] = {0.f, 0.f, 0.f, 0.f, 0.f};
    const float* hm = hmax + (size_t)b * H;
    for (int j = 0; j < H; ++j) {
        float hv = hm[j];
#pragma unroll
        for (int cls = 0; cls < NC; ++cls)
            a[cls] = fmaf(hv, Wout[cls * H + j], a[cls]);
    }
#pragma unroll
    for (int cls = 0; cls < NC; ++cls)
        out[b * NC + cls] = a[cls] + bout[cls];
}

// ---------------- launch ----------------
extern "C" void kernel_launch(void* const* d_in, const int* in_sizes, int n_in,
                              void* d_out, int out_size, void* d_ws, size_t ws_size,
                              hipStream_t stream) {
    const int*   X    = (const int*)  d_in[0];
    const float* emb  = (const float*)d_in[1];
    const float* Wih0 = (const float*)d_in[2];
    const float* Whh0 = (const float*)d_in[3];
    const float* b0   = (const float*)d_in[4];
    const float* Wih1 = (const float*)d_in[5];
    const float* Whh1 = (const float*)d_in[6];
    const float* b1   = (const float*)d_in[7];
    const float* Wout = (const float*)d_in[8];
    const float* bout = (const float*)d_in[9];
    float* out = (float*)d_out;
    char* ws = (char*)d_ws;
    WS w = wsmap(ws);

    k_prep<<<(NW0 + NW1 + 255) / 256, 256, 0, stream>>>(Wih0, Whh0, Wih1, Whh1, ws);
    k_init<<<(524288 + 262144 + NH + 255) / 256, 256, 0, stream>>>(X, ws);

    // Dispatch t computes layer0(t) and layer1(t-1); t = 0..T inclusive.
    for (int t = 0; t <= T; ++t) {
        k_step<<<512, 256, 4 * 64 * 36 * sizeof(float), stream>>>(t, X, emb, b0, b1, ws);
    }

    k_out<<<4, 64, 0, stream>>>(w.hmax, Wout, bout, out);
}